// Round 4
// baseline (321.741 us; speedup 1.0000x reference)
//
#include <hip/hip_runtime.h>
#include <math.h>

// Problem constants: B=4096, T=200, D=64.
// One wave = one batch row. ZERO __syncthreads in the kernel.
#define TT 200
#define DD 64
#define H1STR 20   // H1 row stride in bf16 elems (40B): rows quad*4+r land 8 banks apart

typedef __attribute__((ext_vector_type(8))) short bf16x8;  // 8 bf16 = 4 VGPRs
typedef __attribute__((ext_vector_type(4))) float f32x4;

__device__ __forceinline__ float sigmoidf_(float x) {
    return 1.0f / (1.0f + __expf(-x));
}
__device__ __forceinline__ short f2bf(float x) {
    unsigned u = __float_as_uint(x);
    u += 0x7fff + ((u >> 16) & 1);
    return (short)(u >> 16);
}
__device__ __forceinline__ float bf2f(short s) {
    return __uint_as_float(((unsigned)(unsigned short)s) << 16);
}
__device__ __forceinline__ void build_hi(float4 v0, float4 v1, bf16x8& hi) {
    float xs[8] = {v0.x, v0.y, v0.z, v0.w, v1.x, v1.y, v1.z, v1.w};
    #pragma unroll
    for (int j = 0; j < 8; j++) hi[j] = f2bf(xs[j]);
}

__global__ __launch_bounds__(256) void din_attn_kernel(
    const float* __restrict__ queries,     // [B,64]
    const float* __restrict__ keys,        // [B,200,64]
    const int*   __restrict__ keys_length, // [B]
    const float* __restrict__ W1,          // [256,16]
    const float* __restrict__ b1,          // [16]
    const float* __restrict__ W2,          // [16,8]
    const float* __restrict__ b2,          // [8]
    const float* __restrict__ W3,          // [8,1]
    const float* __restrict__ b3,          // [1]
    const float* __restrict__ W4,          // [64,64]
    const float* __restrict__ b4,          // [64]
    float* __restrict__ out)               // [B,64]
{
    // wave-private LDS slices (no cross-wave sharing -> no barriers)
    __shared__ __align__(16) short H1s[4][208 * H1STR];  // 4*8320 B
    __shared__ __align__(16) float scoresS[4][200];      // 4*800 B
    __shared__ __align__(16) float tmpv[4][64];          // 4*256 B

    const int tid  = threadIdx.x;
    const int w    = tid >> 6;
    const int lane = tid & 63;
    const int m16  = lane & 15;
    const int quad = lane >> 4;
    const int b    = blockIdx.x * 4 + w;
    const int len  = keys_length[b];
    const float* kb = keys + (size_t)b * (TT * DD);

    short* h1p = &H1s[w][0];
    float* scp = &scoresS[w][0];
    float* tvp = &tmpv[w][0];

    // ---- prefetch first scorer tile (t = m16) ----
    const float* kp0 = kb + m16 * 64 + quad * 8;
    float4 c0 = *(const float4*)(kp0);
    float4 c1 = *(const float4*)(kp0 + 4);
    float4 c2 = *(const float4*)(kp0 + 32);
    float4 c3 = *(const float4*)(kp0 + 36);

    // ---- fold W1 directly into MFMA B-fragments (registers, no LDS) ----
    // lane handles n=m16, k = quad*8+j (frag0) and 32+quad*8+j (frag1)
    bf16x8 Bh0, Bl0, Bh1, Bl1;
    float cvec;
    {
        const int d0 = quad * 8;
        const float* qb = queries + b * 64 + d0;
        float4 qv0 = *(const float4*)(qb);
        float4 qv1 = *(const float4*)(qb + 4);
        float4 qv2 = *(const float4*)(qb + 32);
        float4 qv3 = *(const float4*)(qb + 36);
        float qa[8] = {qv0.x, qv0.y, qv0.z, qv0.w, qv1.x, qv1.y, qv1.z, qv1.w};
        float qc[8] = {qv2.x, qv2.y, qv2.z, qv2.w, qv3.x, qv3.y, qv3.z, qv3.w};
        float cp = 0.0f;
        #pragma unroll
        for (int j = 0; j < 8; j++) {
            // half 0: d = d0 + j
            {
                const int d = d0 + j;
                float a  = W1[(0   + d) * 16 + m16];
                float bb = W1[(64  + d) * 16 + m16];
                float cc = W1[(128 + d) * 16 + m16];
                float dd = W1[(192 + d) * 16 + m16];
                float mv = bb - cc + qa[j] * dd;
                cp = fmaf(qa[j], a + cc, cp);
                short hi = f2bf(mv);
                Bh0[j] = hi;
                Bl0[j] = f2bf(mv - bf2f(hi));
            }
            // half 1: d = d0 + j + 32
            {
                const int d = d0 + j + 32;
                float a  = W1[(0   + d) * 16 + m16];
                float bb = W1[(64  + d) * 16 + m16];
                float cc = W1[(128 + d) * 16 + m16];
                float dd = W1[(192 + d) * 16 + m16];
                float mv = bb - cc + qc[j] * dd;
                cp = fmaf(qc[j], a + cc, cp);
                short hi = f2bf(mv);
                Bh1[j] = hi;
                Bl1[j] = f2bf(mv - bf2f(hi));
            }
        }
        // reduce cp over the 4 quads sharing this m16 -> cvec[m16] in-register
        cp += __shfl_xor(cp, 16, 64);
        cp += __shfl_xor(cp, 32, 64);
        cvec = b1[m16] + cp;
    }

    // ---- scorer: 13 t-tiles of MFMA, pipelined keys loads ----
    #pragma unroll 1
    for (int tile = 0; tile < 13; tile++) {
        float4 n0, n1, n2, n3;
        if (tile < 12) {
            int trow = (tile + 1) * 16 + m16;
            if (trow > TT - 1) trow = TT - 1;   // rows 200..207 clamped (masked later)
            const float* kp = kb + trow * 64 + quad * 8;
            n0 = *(const float4*)(kp);
            n1 = *(const float4*)(kp + 4);
            n2 = *(const float4*)(kp + 32);
            n3 = *(const float4*)(kp + 36);
        }
        bf16x8 ah0, ah1;
        build_hi(c0, c1, ah0);
        build_hi(c2, c3, ah1);
        f32x4 acc = {0.f, 0.f, 0.f, 0.f};
        acc = __builtin_amdgcn_mfma_f32_16x16x32_bf16(ah0, Bh0, acc, 0, 0, 0);
        acc = __builtin_amdgcn_mfma_f32_16x16x32_bf16(ah0, Bl0, acc, 0, 0, 0);
        acc = __builtin_amdgcn_mfma_f32_16x16x32_bf16(ah1, Bh1, acc, 0, 0, 0);
        acc = __builtin_amdgcn_mfma_f32_16x16x32_bf16(ah1, Bl1, acc, 0, 0, 0);
        // C layout: col=m16 (=h), row=quad*4+reg (=t within tile)
        const int rb = tile * 16 + quad * 4;
        h1p[(rb + 0) * H1STR + m16] = f2bf(sigmoidf_(acc[0] + cvec));
        h1p[(rb + 1) * H1STR + m16] = f2bf(sigmoidf_(acc[1] + cvec));
        h1p[(rb + 2) * H1STR + m16] = f2bf(sigmoidf_(acc[2] + cvec));
        h1p[(rb + 3) * H1STR + m16] = f2bf(sigmoidf_(acc[3] + cvec));
        c0 = n0; c1 = n1; c2 = n2; c3 = n3;
    }

    // ---- layers 2..3 + mask: t = lane + 64*i  (W2/W3/b2/b3 are wave-uniform loads) ----
    float w3v[8], b2v[8];
    #pragma unroll
    for (int k = 0; k < 8; k++) { w3v[k] = W3[k]; b2v[k] = b2[k]; }
    const float b3v = b3[0];

    float sc[4];
    #pragma unroll
    for (int i = 0; i < 4; i++) {
        int t  = lane + 64 * i;
        int tr = (t > 207) ? 207 : t;
        const uint2* hrow = (const uint2*)&h1p[tr * H1STR];   // 40B rows: 8B-aligned
        uint2 u0 = hrow[0], u1 = hrow[1], u2 = hrow[2], u3 = hrow[3];
        float hv[16];
        hv[0]  = __uint_as_float(u0.x << 16); hv[1]  = __uint_as_float(u0.x & 0xffff0000u);
        hv[2]  = __uint_as_float(u0.y << 16); hv[3]  = __uint_as_float(u0.y & 0xffff0000u);
        hv[4]  = __uint_as_float(u1.x << 16); hv[5]  = __uint_as_float(u1.x & 0xffff0000u);
        hv[6]  = __uint_as_float(u1.y << 16); hv[7]  = __uint_as_float(u1.y & 0xffff0000u);
        hv[8]  = __uint_as_float(u2.x << 16); hv[9]  = __uint_as_float(u2.x & 0xffff0000u);
        hv[10] = __uint_as_float(u2.y << 16); hv[11] = __uint_as_float(u2.y & 0xffff0000u);
        hv[12] = __uint_as_float(u3.x << 16); hv[13] = __uint_as_float(u3.x & 0xffff0000u);
        hv[14] = __uint_as_float(u3.y << 16); hv[15] = __uint_as_float(u3.y & 0xffff0000u);

        float s2[8];
        #pragma unroll
        for (int k = 0; k < 8; k++) s2[k] = b2v[k];
        #pragma unroll
        for (int h = 0; h < 16; h++) {
            const float hh = hv[h];
            const float4* w2r = (const float4*)&W2[h * 8];    // uniform -> s_load
            float4 wa = w2r[0], wb = w2r[1];
            s2[0] = fmaf(hh, wa.x, s2[0]);
            s2[1] = fmaf(hh, wa.y, s2[1]);
            s2[2] = fmaf(hh, wa.z, s2[2]);
            s2[3] = fmaf(hh, wa.w, s2[3]);
            s2[4] = fmaf(hh, wb.x, s2[4]);
            s2[5] = fmaf(hh, wb.y, s2[5]);
            s2[6] = fmaf(hh, wb.z, s2[6]);
            s2[7] = fmaf(hh, wb.w, s2[7]);
        }
        float s3 = b3v;
        #pragma unroll
        for (int k = 0; k < 8; k++) s3 = fmaf(sigmoidf_(s2[k]), w3v[k], s3);
        if (t >= len) s3 = -4294967295.0f;   // NEG_INF (t>=200 is always >= len)
        sc[i] = s3 * 0.125f;                 // / sqrt(64)
    }

    // ---- softmax: pure wave-local butterflies ----
    float m = fmaxf(fmaxf(sc[0], sc[1]), fmaxf(sc[2], sc[3]));
    #pragma unroll
    for (int off = 32; off >= 1; off >>= 1) m = fmaxf(m, __shfl_xor(m, off, 64));
    float p[4];
    float ssum = 0.0f;
    #pragma unroll
    for (int i = 0; i < 4; i++) {
        int t = lane + 64 * i;
        p[i] = (t < TT) ? __expf(sc[i] - m) : 0.0f;  // explicit zero for phantom rows
        ssum += p[i];
    }
    #pragma unroll
    for (int off = 32; off >= 1; off >>= 1) ssum += __shfl_xor(ssum, off, 64);
    const float inv = 1.0f / ssum;
    #pragma unroll
    for (int i = 0; i < 4; i++) {
        int t = lane + 64 * i;
        if (t < TT) scp[t] = p[i];
    }

    // ---- weighted key sum: lane = d, broadcast p via float4 LDS reads ----
    float ws = 0.0f;
    const float4* sp4 = (const float4*)scp;
    #pragma unroll 5
    for (int g = 0; g < 50; g++) {
        float4 pv = sp4[g];
        const float* kq = kb + (g * 4) * 64 + lane;
        ws = fmaf(pv.x, kq[0],   ws);
        ws = fmaf(pv.y, kq[64],  ws);
        ws = fmaf(pv.z, kq[128], ws);
        ws = fmaf(pv.w, kq[192], ws);
    }
    tvp[lane] = ws * inv;

    // ---- epilogue: out = tmpv @ W4 + b4 ; lane = output col ----
    float o = b4[lane];
    const float4* tv4 = (const float4*)tvp;
    #pragma unroll 4
    for (int g = 0; g < 16; g++) {
        float4 tv = tv4[g];
        const float* w4q = W4 + (g * 4) * 64 + lane;
        o = fmaf(tv.x, w4q[0],   o);
        o = fmaf(tv.y, w4q[64],  o);
        o = fmaf(tv.z, w4q[128], o);
        o = fmaf(tv.w, w4q[192], o);
    }
    out[(size_t)b * 64 + lane] = o;
}

extern "C" void kernel_launch(void* const* d_in, const int* in_sizes, int n_in,
                              void* d_out, int out_size, void* d_ws, size_t ws_size,
                              hipStream_t stream) {
    const float* queries     = (const float*)d_in[0];
    const float* keys        = (const float*)d_in[1];
    const int*   keys_length = (const int*)  d_in[2];
    const float* W1 = (const float*)d_in[3];
    const float* b1 = (const float*)d_in[4];
    const float* W2 = (const float*)d_in[5];
    const float* b2 = (const float*)d_in[6];
    const float* W3 = (const float*)d_in[7];
    const float* b3 = (const float*)d_in[8];
    const float* W4 = (const float*)d_in[9];
    const float* b4 = (const float*)d_in[10];
    float* out = (float*)d_out;

    const int Bn = in_sizes[2];   // 4096
    din_attn_kernel<<<Bn / 4, 256, 0, stream>>>(
        queries, keys, keys_length, W1, b1, W2, b2, W3, b3, W4, b4, out);
}

// Round 5
// 319.273 us; speedup vs baseline: 1.0077x; 1.0077x over previous
//
#include <hip/hip_runtime.h>
#include <math.h>

// Problem constants: B=4096, T=200, D=64.
// ONE wave = one batch row, fully fused single pass over keys (read exactly once).
// No __syncthreads; no-max softmax (scores provably bounded: |sc| <~ 0.5).
#define TT 200
#define H1STR 20   // per-tile H1 transpose row stride in bf16 (40B: 8B-aligned, 9/10-coprime banks)

typedef __attribute__((ext_vector_type(8))) short bf16x8;  // 8 bf16 = 4 VGPRs
typedef __attribute__((ext_vector_type(4))) float f32x4;

__device__ __forceinline__ float sigmoidf_(float x) {
    return 1.0f / (1.0f + __expf(-x));
}
__device__ __forceinline__ short f2bf(float x) {
    unsigned u = __float_as_uint(x);
    u += 0x7fff + ((u >> 16) & 1);
    return (short)(u >> 16);
}
__device__ __forceinline__ float bf2f(short s) {
    return __uint_as_float(((unsigned)(unsigned short)s) << 16);
}
__device__ __forceinline__ void build_hi(float4 v0, float4 v1, bf16x8& hi) {
    float xs[8] = {v0.x, v0.y, v0.z, v0.w, v1.x, v1.y, v1.z, v1.w};
    #pragma unroll
    for (int j = 0; j < 8; j++) hi[j] = f2bf(xs[j]);
}

__global__ __launch_bounds__(64, 4) void din_attn_kernel(
    const float* __restrict__ queries,     // [B,64]
    const float* __restrict__ keys,        // [B,200,64]
    const int*   __restrict__ keys_length, // [B]
    const float* __restrict__ W1,          // [256,16]
    const float* __restrict__ b1,          // [16]
    const float* __restrict__ W2,          // [16,8]
    const float* __restrict__ b2,          // [8]
    const float* __restrict__ W3,          // [8,1]
    const float* __restrict__ b3,          // [1]
    const float* __restrict__ W4,          // [64,64]
    const float* __restrict__ b4,          // [64]
    float* __restrict__ out)               // [B,64]
{
    __shared__ __align__(8)  short h1t[16 * H1STR];  // 640 B: per-tile H1 transpose
    __shared__ __align__(16) float tmpv[64];         // 256 B: attn-weighted key sum

    const int lane = threadIdx.x;          // 64-thread block = exactly one wave
    const int m16  = lane & 15;
    const int quad = lane >> 4;
    const int b    = blockIdx.x;
    const int len  = keys_length[b];       // wave-uniform -> s_load
    const float* kb = keys + (size_t)b * (TT * 64);

    // ---- prefetch first scorer tile (t = m16, k-cols quad*8+j and +32) ----
    const float* kp0 = kb + m16 * 64 + quad * 8;
    float4 c0 = *(const float4*)(kp0);
    float4 c1 = *(const float4*)(kp0 + 4);
    float4 c2 = *(const float4*)(kp0 + 32);
    float4 c3 = *(const float4*)(kp0 + 36);

    // ---- fold W1 directly into MFMA B-fragments (registers only) ----
    // lane owns n=m16, k = quad*8+j (frag0) and 32+quad*8+j (frag1)
    bf16x8 Bh0, Bl0, Bh1, Bl1;
    float cvec;
    {
        const int d0 = quad * 8;
        const float* qb = queries + b * 64 + d0;
        float4 qv0 = *(const float4*)(qb);
        float4 qv1 = *(const float4*)(qb + 4);
        float4 qv2 = *(const float4*)(qb + 32);
        float4 qv3 = *(const float4*)(qb + 36);
        float qa[8] = {qv0.x, qv0.y, qv0.z, qv0.w, qv1.x, qv1.y, qv1.z, qv1.w};
        float qc[8] = {qv2.x, qv2.y, qv2.z, qv2.w, qv3.x, qv3.y, qv3.z, qv3.w};
        float cp = 0.0f;
        #pragma unroll
        for (int j = 0; j < 8; j++) {
            {
                const int d = d0 + j;
                float a  = W1[(0   + d) * 16 + m16];
                float bb = W1[(64  + d) * 16 + m16];
                float cc = W1[(128 + d) * 16 + m16];
                float dd = W1[(192 + d) * 16 + m16];
                float mv = bb - cc + qa[j] * dd;
                cp = fmaf(qa[j], a + cc, cp);
                short hi = f2bf(mv);
                Bh0[j] = hi;
                Bl0[j] = f2bf(mv - bf2f(hi));
            }
            {
                const int d = d0 + j + 32;
                float a  = W1[(0   + d) * 16 + m16];
                float bb = W1[(64  + d) * 16 + m16];
                float cc = W1[(128 + d) * 16 + m16];
                float dd = W1[(192 + d) * 16 + m16];
                float mv = bb - cc + qc[j] * dd;
                cp = fmaf(qc[j], a + cc, cp);
                short hi = f2bf(mv);
                Bh1[j] = hi;
                Bl1[j] = f2bf(mv - bf2f(hi));
            }
        }
        cp += __shfl_xor(cp, 16, 64);
        cp += __shfl_xor(cp, 32, 64);
        cvec = b1[m16] + cp;
    }

    // ---- uniform tiny weights (scalarized loads) ----
    float w3v[8], b2v[8];
    #pragma unroll
    for (int k = 0; k < 8; k++) { w3v[k] = W3[k]; b2v[k] = b2[k]; }
    const float b3v = b3[0];

    // ---- fused tile loop: MFMA scorer -> MLP -> p -> weighted-sum accumulate ----
    float ws0[8], ws1[8];
    #pragma unroll
    for (int j = 0; j < 8; j++) { ws0[j] = 0.0f; ws1[j] = 0.0f; }
    float ssum = 0.0f;

    #pragma unroll 1
    for (int tile = 0; tile < 13; tile++) {
        // prefetch next tile's keys
        float4 n0, n1, n2, n3;
        if (tile < 12) {
            int trow = (tile + 1) * 16 + m16;
            if (trow > TT - 1) trow = TT - 1;
            const float* kp = kb + trow * 64 + quad * 8;
            n0 = *(const float4*)(kp);
            n1 = *(const float4*)(kp + 4);
            n2 = *(const float4*)(kp + 32);
            n3 = *(const float4*)(kp + 36);
        }

        // layer-1 via MFMA (split-bf16 B for accuracy)
        bf16x8 ah0, ah1;
        build_hi(c0, c1, ah0);
        build_hi(c2, c3, ah1);
        f32x4 acc = {0.f, 0.f, 0.f, 0.f};
        acc = __builtin_amdgcn_mfma_f32_16x16x32_bf16(ah0, Bh0, acc, 0, 0, 0);
        acc = __builtin_amdgcn_mfma_f32_16x16x32_bf16(ah0, Bl0, acc, 0, 0, 0);
        acc = __builtin_amdgcn_mfma_f32_16x16x32_bf16(ah1, Bh1, acc, 0, 0, 0);
        acc = __builtin_amdgcn_mfma_f32_16x16x32_bf16(ah1, Bl1, acc, 0, 0, 0);

        // C layout: col=m16 (=h), row=quad*4+r (=t in tile). Transpose via tiny LDS.
        #pragma unroll
        for (int r = 0; r < 4; r++)
            h1t[(quad * 4 + r) * H1STR + m16] = f2bf(sigmoidf_(acc[r] + cvec));
        __asm__ volatile("s_waitcnt lgkmcnt(0)" ::: "memory");

        // layers 2..3 per lane for t = tile*16 + m16 (quad-redundant on purpose)
        const uint2* hrow = (const uint2*)&h1t[m16 * H1STR];
        uint2 u0 = hrow[0], u1 = hrow[1], u2 = hrow[2], u3 = hrow[3];
        float hv[16];
        hv[0]  = __uint_as_float(u0.x << 16); hv[1]  = __uint_as_float(u0.x & 0xffff0000u);
        hv[2]  = __uint_as_float(u0.y << 16); hv[3]  = __uint_as_float(u0.y & 0xffff0000u);
        hv[4]  = __uint_as_float(u1.x << 16); hv[5]  = __uint_as_float(u1.x & 0xffff0000u);
        hv[6]  = __uint_as_float(u1.y << 16); hv[7]  = __uint_as_float(u1.y & 0xffff0000u);
        hv[8]  = __uint_as_float(u2.x << 16); hv[9]  = __uint_as_float(u2.x & 0xffff0000u);
        hv[10] = __uint_as_float(u2.y << 16); hv[11] = __uint_as_float(u2.y & 0xffff0000u);
        hv[12] = __uint_as_float(u3.x << 16); hv[13] = __uint_as_float(u3.x & 0xffff0000u);
        hv[14] = __uint_as_float(u3.y << 16); hv[15] = __uint_as_float(u3.y & 0xffff0000u);

        float s2[8];
        #pragma unroll
        for (int k = 0; k < 8; k++) s2[k] = b2v[k];
        #pragma unroll
        for (int h = 0; h < 16; h++) {
            const float hh = hv[h];
            const float4* w2r = (const float4*)&W2[h * 8];   // uniform -> s_load
            float4 wa = w2r[0], wb = w2r[1];
            s2[0] = fmaf(hh, wa.x, s2[0]);
            s2[1] = fmaf(hh, wa.y, s2[1]);
            s2[2] = fmaf(hh, wa.z, s2[2]);
            s2[3] = fmaf(hh, wa.w, s2[3]);
            s2[4] = fmaf(hh, wb.x, s2[4]);
            s2[5] = fmaf(hh, wb.y, s2[5]);
            s2[6] = fmaf(hh, wb.z, s2[6]);
            s2[7] = fmaf(hh, wb.w, s2[7]);
        }
        float s3 = b3v;
        #pragma unroll
        for (int k = 0; k < 8; k++) s3 = fmaf(sigmoidf_(s2[k]), w3v[k], s3);
        const float sc = s3 * 0.125f;   // / sqrt(64); |sc| bounded ~O(0.5): exp safe w/o max

        const int t = tile * 16 + m16;
        // p: normal rows exp(sc) if t<len; masked -> 0. len==0: ref softmax over all-equal
        // NEG_INF scores -> uniform; emulate with p=1 for t<200.
        float p;
        if (len == 0) p = (t < TT) ? 1.0f : 0.0f;
        else          p = (t < len) ? __expf(sc) : 0.0f;
        ssum += p;

        // weighted-sum accumulate while this tile's keys are still in registers
        ws0[0] = fmaf(p, c0.x, ws0[0]);
        ws0[1] = fmaf(p, c0.y, ws0[1]);
        ws0[2] = fmaf(p, c0.z, ws0[2]);
        ws0[3] = fmaf(p, c0.w, ws0[3]);
        ws0[4] = fmaf(p, c1.x, ws0[4]);
        ws0[5] = fmaf(p, c1.y, ws0[5]);
        ws0[6] = fmaf(p, c1.z, ws0[6]);
        ws0[7] = fmaf(p, c1.w, ws0[7]);
        ws1[0] = fmaf(p, c2.x, ws1[0]);
        ws1[1] = fmaf(p, c2.y, ws1[1]);
        ws1[2] = fmaf(p, c2.z, ws1[2]);
        ws1[3] = fmaf(p, c2.w, ws1[3]);
        ws1[4] = fmaf(p, c3.x, ws1[4]);
        ws1[5] = fmaf(p, c3.y, ws1[5]);
        ws1[6] = fmaf(p, c3.z, ws1[6]);
        ws1[7] = fmaf(p, c3.w, ws1[7]);

        c0 = n0; c1 = n1; c2 = n2; c3 = n3;
    }

    // ---- reduce ws over the 16 m16-lanes (t coverage) + ssum; quads stay redundant ----
    #pragma unroll
    for (int mask = 1; mask <= 8; mask <<= 1) {
        ssum += __shfl_xor(ssum, mask, 64);
        #pragma unroll
        for (int j = 0; j < 8; j++) {
            ws0[j] += __shfl_xor(ws0[j], mask, 64);
            ws1[j] += __shfl_xor(ws1[j], mask, 64);
        }
    }
    const float inv = 1.0f / ssum;

    // scatter normalized sums to tmpv[d]: lane (quad, m16==j) owns d=quad*8+j and +32
    #pragma unroll
    for (int j = 0; j < 8; j++) {
        if (m16 == j) {
            tmpv[quad * 8 + j]      = ws0[j] * inv;
            tmpv[32 + quad * 8 + j] = ws1[j] * inv;
        }
    }
    __asm__ volatile("s_waitcnt lgkmcnt(0)" ::: "memory");

    // ---- epilogue: out = tmpv @ W4 + b4 ; lane = output col ----
    float o = b4[lane];
    const float4* tv4 = (const float4*)tmpv;
    #pragma unroll 4
    for (int g = 0; g < 16; g++) {
        float4 tv = tv4[g];
        const float* w4q = W4 + (g * 4) * 64 + lane;
        o = fmaf(tv.x, w4q[0],   o);
        o = fmaf(tv.y, w4q[64],  o);
        o = fmaf(tv.z, w4q[128], o);
        o = fmaf(tv.w, w4q[192], o);
    }
    out[(size_t)b * 64 + lane] = o;
}

extern "C" void kernel_launch(void* const* d_in, const int* in_sizes, int n_in,
                              void* d_out, int out_size, void* d_ws, size_t ws_size,
                              hipStream_t stream) {
    const float* queries     = (const float*)d_in[0];
    const float* keys        = (const float*)d_in[1];
    const int*   keys_length = (const int*)  d_in[2];
    const float* W1 = (const float*)d_in[3];
    const float* b1 = (const float*)d_in[4];
    const float* W2 = (const float*)d_in[5];
    const float* b2 = (const float*)d_in[6];
    const float* W3 = (const float*)d_in[7];
    const float* b3 = (const float*)d_in[8];
    const float* W4 = (const float*)d_in[9];
    const float* b4 = (const float*)d_in[10];
    float* out = (float*)d_out;

    const int Bn = in_sizes[2];   // 4096
    din_attn_kernel<<<Bn, 64, 0, stream>>>(
        queries, keys, keys_length, W1, b1, W2, b2, W3, b3, W4, b4, out);
}